// Round 5
// baseline (374.276 us; speedup 1.0000x reference)
//
#include <hip/hip_runtime.h>
#include <math.h>

// N=768, T=8, H=128, F=128, NZ=64, G=64, D=320, n_next=12
// ws offsets in 4-byte units (floats or packed-bf16 dwords). Total ~2.0 MB.
#define H_OFF    0         // f32 [768][128]
#define C_OFF    98304     // f32 [768][128]
#define G_OFF    196608    // f32 [768][64]
#define S0_OFF   245760    // f32 [768]
#define WTD_OFF  246528    // f32 [768][128]
#define TIHP_OFF 344832    // u32 [64][512]  : dword = bf16(Wih[r][2kp]) | bf16(Wih[r][2kp+1])<<16
#define THHP_OFF 377600    // u32 [64][512]
#define TD1P_OFF 410368    // u32 [160][320]
#define TD2P_OFF 461568    // u32 [160][160]
#define TD3P_OFF 487168    // u32 [80][80]
#define TWA_OFF  493568    // f32 [128][128] (WaT)
#define BZ_OFF   509952    // f32 [512] (bih+bhh)

__device__ __forceinline__ float sigm(float x) { return 1.0f / (1.0f + __expf(-x)); }
__device__ __forceinline__ float lrelu(float u) { return u >= 0.f ? u : 0.2f * u; }

__device__ __forceinline__ unsigned bf16rn(float f) {
  unsigned u = __float_as_uint(f);
  unsigned r = u + 0x7fffu + ((u >> 16) & 1u);   // round-to-nearest-even
  return r >> 16;
}
__device__ __forceinline__ unsigned pack2(float a, float b) {
  return bf16rn(a) | (bf16rn(b) << 16);
}
#define UNPK(u_, w0_, w1_) \
  float w0_ = __uint_as_float((u_) << 16); \
  float w1_ = __uint_as_float((u_) & 0xffff0000u);

// ---------------- one-time transpose + bf16 k-pair pack + bias fold ----------------
__global__ __launch_bounds__(256) void k_tr(
    const float* __restrict__ Wih, const float* __restrict__ Whh,
    const float* __restrict__ Wd1, const float* __restrict__ Wd2,
    const float* __restrict__ Wd3, const float* __restrict__ Wa,
    const float* __restrict__ bih, const float* __restrict__ bhh,
    float* __restrict__ ws)
{
  const int idx = blockIdx.x * 256 + threadIdx.x;
  unsigned* wsu = (unsigned*)ws;
  if (idx < 32768) {  // [512][128] -> packed [64][512]
    int kp = idx >> 9, r = idx & 511;
    wsu[TIHP_OFF + idx] = pack2(Wih[(size_t)r * 128 + 2 * kp], Wih[(size_t)r * 128 + 2 * kp + 1]);
    wsu[THHP_OFF + idx] = pack2(Whh[(size_t)r * 128 + 2 * kp], Whh[(size_t)r * 128 + 2 * kp + 1]);
  }
  if (idx < 51200) {  // Wd1 [320][320] -> [160][320]
    int kp = idx / 320, r = idx % 320;
    wsu[TD1P_OFF + idx] = pack2(Wd1[(size_t)r * 320 + 2 * kp], Wd1[(size_t)r * 320 + 2 * kp + 1]);
  }
  if (idx < 25600) {  // Wd2 [160][320] -> [160][160]
    int kp = idx / 160, r = idx % 160;
    wsu[TD2P_OFF + idx] = pack2(Wd2[(size_t)r * 320 + 2 * kp], Wd2[(size_t)r * 320 + 2 * kp + 1]);
  }
  if (idx < 6400) {   // Wd3 [80][160] -> [80][80]
    int kp = idx / 80, r = idx % 80;
    wsu[TD3P_OFF + idx] = pack2(Wd3[(size_t)r * 160 + 2 * kp], Wd3[(size_t)r * 160 + 2 * kp + 1]);
  }
  if (idx < 16384) { int k = idx >> 7, r = idx & 127; ws[TWA_OFF + idx] = Wa[(size_t)r * 128 + k]; }
  if (idx < 512)   ws[BZ_OFF + idx] = bih[idx] + bhh[idx];
}

// ---------------- encoder LSTM: emb fused, 3 agents/block, 8 waves ----------------
__global__ __launch_bounds__(512) void k_enc(
    const float* __restrict__ obsv, const float* __restrict__ Wemb,
    const float* __restrict__ bemb, float* __restrict__ ws)
{
  __shared__ float hS[3][128], cS[3][128], zS[3][512], xeS[3][128];
  __shared__ float WembS[512], bembS[128];
  const int tid = threadIdx.x;
  const int wid = tid >> 6, lane = tid & 63;
  const int n0 = blockIdx.x * 3;
  const int row = wid * 64 + lane;

  WembS[tid] = Wemb[tid];
  if (tid < 128) bembS[tid] = bemb[tid];
  if (tid < 384) { int a = tid >> 7, j = tid & 127; hS[a][j] = 0.f; cS[a][j] = 0.f; }
  __syncthreads();

  const float bzv = ws[BZ_OFF + row];
  const unsigned* wihp = (const unsigned*)(ws + TIHP_OFF);
  const unsigned* whhp = (const unsigned*)(ws + THHP_OFF);

  for (int step = 0; step < 8; ++step) {
    if (tid < 384) {
      int a = tid >> 7, j = tid & 127;
      float4 ob = *(const float4*)&obsv[((size_t)(n0 + a) * 8 + step) * 4];
      float4 w = *(const float4*)&WembS[j * 4];
      xeS[a][j] = bembS[j] + ob.x * w.x + ob.y * w.y + ob.z * w.z + ob.w * w.w;
    }
    __syncthreads();
    float a0 = bzv, a1 = bzv, a2 = bzv;
#pragma unroll 4
    for (int kp = 0; kp < 64; ++kp) {
      unsigned u = wihp[kp * 512 + row];
      UNPK(u, w0, w1)
      a0 += w0 * xeS[0][2 * kp] + w1 * xeS[0][2 * kp + 1];
      a1 += w0 * xeS[1][2 * kp] + w1 * xeS[1][2 * kp + 1];
      a2 += w0 * xeS[2][2 * kp] + w1 * xeS[2][2 * kp + 1];
    }
    if (step > 0) {
#pragma unroll 4
      for (int kp = 0; kp < 64; ++kp) {
        unsigned u = whhp[kp * 512 + row];
        UNPK(u, w0, w1)
        a0 += w0 * hS[0][2 * kp] + w1 * hS[0][2 * kp + 1];
        a1 += w0 * hS[1][2 * kp] + w1 * hS[1][2 * kp + 1];
        a2 += w0 * hS[2][2 * kp] + w1 * hS[2][2 * kp + 1];
      }
    }
    zS[0][row] = a0; zS[1][row] = a1; zS[2][row] = a2;
    __syncthreads();
    if (tid < 384) {
      int a = tid >> 7, j = tid & 127;
      float ci = sigm(zS[a][j + 128]) * cS[a][j] + sigm(zS[a][j]) * tanhf(zS[a][j + 256]);
      cS[a][j] = ci;
      hS[a][j] = sigm(zS[a][j + 384]) * tanhf(ci);
    }
    __syncthreads();
  }
  if (tid < 384) {
    int a = tid >> 7, j = tid & 127;
    ws[H_OFF + (size_t)(n0 + a) * 128 + j] = hS[a][j];
    ws[C_OFF + (size_t)(n0 + a) * 128 + j] = cS[a][j];
  }
}

// ---------------- social fold: Wh = h@Wa^T + ba ; g = Wf3^T Wh ; s0 = bf3 . Wh ----------------
__global__ __launch_bounds__(128) void k_social(
    const float* __restrict__ ba, const float* __restrict__ Wf3,
    const float* __restrict__ bf3, float* __restrict__ ws)
{
  __shared__ float hsh[128];
  __shared__ float Wh[128];
  const int n = blockIdx.x, t = threadIdx.x;
  hsh[t] = ws[H_OFF + (size_t)n * 128 + t];
  __syncthreads();
  float acc = ba[t];
#pragma unroll 8
  for (int k = 0; k < 128; ++k) acc += ws[TWA_OFF + (size_t)k * 128 + t] * hsh[k];
  Wh[t] = acc;
  __syncthreads();
  if (t < 64) {
    float g = 0.f;
#pragma unroll 8
    for (int f = 0; f < 128; ++f) g += Wf3[(size_t)f * 64 + t] * Wh[f];
    ws[G_OFF + (size_t)n * 64 + t] = g;
  } else {
    int l = t - 64;
    float p = bf3[l] * Wh[l] + bf3[l + 64] * Wh[l + 64];
    for (int off = 32; off > 0; off >>= 1) p += __shfl_xor(p, off);
    if (l == 0) ws[S0_OFF + n] = p;
  }
}

// ---------------- pair features + MLP(3->32->64) + sigma + softmax + S ----------------
__global__ __launch_bounds__(64) void k_attn(
    const float* __restrict__ obsv, const float* __restrict__ Wf1,
    const float* __restrict__ bf1, const float* __restrict__ Wf2,
    const float* __restrict__ bf2, float* __restrict__ ws)
{
  __shared__ float w1[96];
  __shared__ float b1[32];
  __shared__ float w2[2048];
  __shared__ float b2[64];
  __shared__ float attn_s[64];
  __shared__ float xi[4];

  const int i = blockIdx.x;
  const int b = i >> 6;
  const int lane = threadIdx.x;
  const int jn = (b << 6) + lane;

  for (int e = lane; e < 96; e += 64) w1[e] = Wf1[e];
  if (lane < 32) b1[lane] = bf1[lane];
  for (int e = lane; e < 2048; e += 64) w2[e] = Wf2[e];
  b2[lane] = bf2[lane];
  if (lane < 4) xi[lane] = obsv[((size_t)i * 8 + 7) * 4 + lane];
  __syncthreads();

  float4 xj = *(const float4*)&obsv[((size_t)jn * 8 + 7) * 4];
  float dpx = xi[0] - xj.x, dpy = xi[1] - xj.y;
  float vix = xi[2], viy = xi[3];
  float dvx = vix - xj.z, dvy = viy - xj.w;
  float l2 = sqrtf(dpx * dpx + dpy * dpy);
  float vnorm = sqrtf(vix * vix + viy * viy);
  float cosv = (dpx * vix + dpy * viy) / (l2 * vnorm + 1e-6f);
  float dv2 = dvx * dvx + dvy * dvy;
  float ttca = -(dpx * dvx + dpy * dvy) / (dv2 + 1e-6f);
  float cax = dpx + ttca * dvx, cay = dpy + ttca * dvy;
  float dca = sqrtf(cax * cax + cay * cay);

  float e1[32];
#pragma unroll
  for (int r = 0; r < 32; ++r)
    e1[r] = fmaxf(w1[r * 3 + 0] * l2 + w1[r * 3 + 1] * cosv + w1[r * 3 + 2] * dca + b1[r], 0.f);

  const float* gp = &ws[G_OFF + (size_t)jn * 64];
  float sig = ws[S0_OFF + jn];
  for (int r = 0; r < 64; ++r) {
    float a2 = b2[r];
#pragma unroll
    for (int k4 = 0; k4 < 8; ++k4) {
      float4 w = *(const float4*)&w2[r * 32 + k4 * 4];
      a2 += w.x * e1[k4 * 4 + 0] + w.y * e1[k4 * 4 + 1] + w.z * e1[k4 * 4 + 2] + w.w * e1[k4 * 4 + 3];
    }
    a2 = fmaxf(a2, 0.f);
    sig += a2 * gp[r];
  }
  if (lane == (i & 63)) sig = -1000.f;

  float m = sig;
  for (int off = 32; off > 0; off >>= 1) m = fmaxf(m, __shfl_xor(m, off));
  float ex = __expf(sig - m);
  float ssum = ex;
  for (int off = 32; off > 0; off >>= 1) ssum += __shfl_xor(ssum, off);
  attn_s[lane] = ex / ssum;
  __syncthreads();

  const float* hbase = &ws[H_OFF + (size_t)(b << 6) * 128];
  float s0a = 0.f, s1a = 0.f;
  for (int j = 0; j < 64; ++j) {
    float aj = attn_s[j];
    s0a += aj * hbase[(size_t)j * 128 + lane];
    s1a += aj * hbase[(size_t)j * 128 + 64 + lane];
  }
  ws[WTD_OFF + (size_t)i * 128 + lane] = s0a;
  ws[WTD_OFF + (size_t)i * 128 + 64 + lane] = s1a;
}

// ---------------- decoder: 12 fused steps, 3 agents/block, grid 256, bf16 weights ----------------
__global__ __launch_bounds__(512) void k_dec(
    const float* __restrict__ obsv, const float* __restrict__ noise,
    const float* __restrict__ Wemb, const float* __restrict__ bemb,
    const float* __restrict__ bd1, const float* __restrict__ bd2,
    const float* __restrict__ bd3, const float* __restrict__ bd4,
    const float* __restrict__ Wd4,
    float* __restrict__ ws, float* __restrict__ out)
{
  __shared__ float inpS[3][320], u1S[3][320], u2S[3][160], u3S[3][80];
  __shared__ float cS[3][128], xeS[3][128], zS[3][512];
  __shared__ float lastS[3][4];
  __shared__ float bd1S[320], bd2S[160], bd3S[80], bd4S[2], Wd4S[160];
  __shared__ float WembS[512], bembS[128], bzS[512];

  const int tid = threadIdx.x;
  const int wid = tid >> 6, lane = tid & 63;
  const int n0 = blockIdx.x * 3;

  const unsigned* wp1 = (const unsigned*)(ws + TD1P_OFF);
  const unsigned* wp2 = (const unsigned*)(ws + TD2P_OFF);
  const unsigned* wp3 = (const unsigned*)(ws + TD3P_OFF);
  const unsigned* wihp = (const unsigned*)(ws + TIHP_OFF);
  const unsigned* whhp = (const unsigned*)(ws + THHP_OFF);

  if (tid < 384) {
    int a = tid >> 7, j = tid & 127;
    inpS[a][j] = ws[H_OFF + (size_t)(n0 + a) * 128 + j];
    inpS[a][128 + j] = ws[WTD_OFF + (size_t)(n0 + a) * 128 + j];
    if (j < 64) inpS[a][256 + j] = noise[(size_t)(n0 + a) * 64 + j];
    cS[a][j] = ws[C_OFF + (size_t)(n0 + a) * 128 + j];
  }
  WembS[tid] = Wemb[tid];
  bzS[tid] = ws[BZ_OFF + tid];
  if (tid < 320) bd1S[tid] = bd1[tid];
  if (tid < 160) { bd2S[tid] = bd2[tid]; Wd4S[tid] = Wd4[tid]; }
  if (tid < 128) bembS[tid] = bemb[tid];
  if (tid < 80) bd3S[tid] = bd3[tid];
  if (tid < 2) bd4S[tid] = bd4[tid];
  if (tid < 12) {
    int a = tid >> 2, r = tid & 3;
    lastS[a][r] = obsv[((size_t)(n0 + a) * 8 + 7) * 4 + r];
  }
  __syncthreads();

  for (int s = 0; s < 12; ++s) {
    // u1 = lrelu(inp @ Wd1^T + bd1): 320 rows, waves 0..4 row-stationary, k-pairs
    if (wid < 5) {
      const int r = wid * 64 + lane;
      float a0 = bd1S[r], a1 = a0, a2 = a0;
#pragma unroll 4
      for (int kp = 0; kp < 160; ++kp) {
        unsigned u = wp1[kp * 320 + r];
        UNPK(u, w0, w1)
        a0 += w0 * inpS[0][2 * kp] + w1 * inpS[0][2 * kp + 1];
        a1 += w0 * inpS[1][2 * kp] + w1 * inpS[1][2 * kp + 1];
        a2 += w0 * inpS[2][2 * kp] + w1 * inpS[2][2 * kp + 1];
      }
      u1S[0][r] = lrelu(a0); u1S[1][r] = lrelu(a1); u1S[2][r] = lrelu(a2);
    }
    __syncthreads();
    // u2: 160 rows, k-pairs 160 split in 2 halves across lane groups
    if (wid < 5) {
      const int r = wid * 32 + (lane & 31);
      const int kb = (lane >> 5) * 80;
      float a0 = 0.f, a1 = 0.f, a2 = 0.f;
#pragma unroll 4
      for (int i2 = 0; i2 < 80; ++i2) {
        int kp = kb + i2;
        unsigned u = wp2[kp * 160 + r];
        UNPK(u, w0, w1)
        a0 += w0 * u1S[0][2 * kp] + w1 * u1S[0][2 * kp + 1];
        a1 += w0 * u1S[1][2 * kp] + w1 * u1S[1][2 * kp + 1];
        a2 += w0 * u1S[2][2 * kp] + w1 * u1S[2][2 * kp + 1];
      }
      a0 += __shfl_xor(a0, 32); a1 += __shfl_xor(a1, 32); a2 += __shfl_xor(a2, 32);
      if (lane < 32) {
        float bb = bd2S[r];
        u2S[0][r] = lrelu(a0 + bb); u2S[1][r] = lrelu(a1 + bb); u2S[2][r] = lrelu(a2 + bb);
      }
    }
    __syncthreads();
    // u3: 80 rows, k-pairs 80 split in 4 quarters across lane groups
    if (wid < 5) {
      const int r = wid * 16 + (lane & 15);
      const int kb = (lane >> 4) * 20;
      float a0 = 0.f, a1 = 0.f, a2 = 0.f;
#pragma unroll 4
      for (int i2 = 0; i2 < 20; ++i2) {
        int kp = kb + i2;
        unsigned u = wp3[kp * 80 + r];
        UNPK(u, w0, w1)
        a0 += w0 * u2S[0][2 * kp] + w1 * u2S[0][2 * kp + 1];
        a1 += w0 * u2S[1][2 * kp] + w1 * u2S[1][2 * kp + 1];
        a2 += w0 * u2S[2][2 * kp] + w1 * u2S[2][2 * kp + 1];
      }
      a0 += __shfl_xor(a0, 16); a1 += __shfl_xor(a1, 16); a2 += __shfl_xor(a2, 16);
      a0 += __shfl_xor(a0, 32); a1 += __shfl_xor(a1, 32); a2 += __shfl_xor(a2, 32);
      if (lane < 16) {
        float bb = bd3S[r];
        u3S[0][r] = a0 + bb; u3S[1][r] = a1 + bb; u3S[2][r] = a2 + bb;
      }
    }
    __syncthreads();
    // v = u3 @ Wd4^T + bd4 (2 rows); position update; output
    if (wid < 3) {
      const int a = wid;
      float q0 = Wd4S[lane] * u3S[a][lane];
      float q1 = Wd4S[80 + lane] * u3S[a][lane];
      if (lane < 16) {
        q0 += Wd4S[64 + lane] * u3S[a][64 + lane];
        q1 += Wd4S[144 + lane] * u3S[a][64 + lane];
      }
      for (int off = 32; off > 0; off >>= 1) { q0 += __shfl_xor(q0, off); q1 += __shfl_xor(q1, off); }
      if (lane == 0) {
        float v0 = q0 + bd4S[0], v1 = q1 + bd4S[1];
        float p0 = v0 + lastS[a][0], p1 = v1 + lastS[a][1];
        lastS[a][0] = p0; lastS[a][1] = p1; lastS[a][2] = v0; lastS[a][3] = v1;
        float* op = &out[(size_t)(n0 + a) * 48 + s * 4];
        op[0] = p0; op[1] = p1; op[2] = v0; op[3] = v1;
      }
    }
    __syncthreads();
    // xe = new_last @ Wemb^T + bemb
    if (tid < 384) {
      int a = tid >> 7, j = tid & 127;
      float4 w = *(const float4*)&WembS[j * 4];
      xeS[a][j] = bembS[j] + lastS[a][0] * w.x + lastS[a][1] * w.y + lastS[a][2] * w.z + lastS[a][3] * w.w;
    }
    __syncthreads();
    // z = xe @ Wih^T + h @ Whh^T + bz: 512 rows, all 8 waves, k-pairs
    {
      const int row = wid * 64 + lane;
      float a0 = bzS[row], a1 = a0, a2 = a0;
#pragma unroll 4
      for (int kp = 0; kp < 64; ++kp) {
        unsigned u = wihp[kp * 512 + row];
        UNPK(u, w0, w1)
        a0 += w0 * xeS[0][2 * kp] + w1 * xeS[0][2 * kp + 1];
        a1 += w0 * xeS[1][2 * kp] + w1 * xeS[1][2 * kp + 1];
        a2 += w0 * xeS[2][2 * kp] + w1 * xeS[2][2 * kp + 1];
      }
#pragma unroll 4
      for (int kp = 0; kp < 64; ++kp) {
        unsigned u = whhp[kp * 512 + row];
        UNPK(u, w0, w1)
        a0 += w0 * inpS[0][2 * kp] + w1 * inpS[0][2 * kp + 1];
        a1 += w0 * inpS[1][2 * kp] + w1 * inpS[1][2 * kp + 1];
        a2 += w0 * inpS[2][2 * kp] + w1 * inpS[2][2 * kp + 1];
      }
      zS[0][row] = a0; zS[1][row] = a1; zS[2][row] = a2;
    }
    __syncthreads();
    // gates: update c and h (h lives in inpS[:, 0:128])
    if (tid < 384) {
      int a = tid >> 7, j = tid & 127;
      float ci = sigm(zS[a][j + 128]) * cS[a][j] + sigm(zS[a][j]) * tanhf(zS[a][j + 256]);
      cS[a][j] = ci;
      inpS[a][j] = sigm(zS[a][j + 384]) * tanhf(ci);
    }
    __syncthreads();
  }
}

extern "C" void kernel_launch(void* const* d_in, const int* in_sizes, int n_in,
                              void* d_out, int out_size, void* d_ws, size_t ws_size,
                              hipStream_t stream)
{
  const float* obsv = (const float*)d_in[0];
  const float* noise = (const float*)d_in[1];
  const float* Wemb = (const float*)d_in[2];
  const float* bemb = (const float*)d_in[3];
  const float* Wih = (const float*)d_in[4];
  const float* Whh = (const float*)d_in[5];
  const float* bih = (const float*)d_in[6];
  const float* bhh = (const float*)d_in[7];
  const float* Wf1 = (const float*)d_in[8];
  const float* bf1 = (const float*)d_in[9];
  const float* Wf2 = (const float*)d_in[10];
  const float* bf2 = (const float*)d_in[11];
  const float* Wf3 = (const float*)d_in[12];
  const float* bf3 = (const float*)d_in[13];
  const float* Wa = (const float*)d_in[14];
  const float* ba = (const float*)d_in[15];
  const float* Wd1 = (const float*)d_in[16];
  const float* bd1 = (const float*)d_in[17];
  const float* Wd2 = (const float*)d_in[18];
  const float* bd2 = (const float*)d_in[19];
  const float* Wd3 = (const float*)d_in[20];
  const float* bd3 = (const float*)d_in[21];
  const float* Wd4 = (const float*)d_in[22];
  const float* bd4 = (const float*)d_in[23];
  float* ws = (float*)d_ws;
  float* out = (float*)d_out;

  k_tr<<<200, 256, 0, stream>>>(Wih, Whh, Wd1, Wd2, Wd3, Wa, bih, bhh, ws);
  k_enc<<<256, 512, 0, stream>>>(obsv, Wemb, bemb, ws);
  k_social<<<768, 128, 0, stream>>>(ba, Wf3, bf3, ws);
  k_attn<<<768, 64, 0, stream>>>(obsv, Wf1, bf1, Wf2, bf2, ws);
  k_dec<<<256, 512, 0, stream>>>(obsv, noise, Wemb, bemb, bd1, bd2, bd3, bd4, Wd4, ws, out);
}

// Round 6
// 310.012 us; speedup vs baseline: 1.2073x; 1.2073x over previous
//
#include <hip/hip_runtime.h>
#include <math.h>

// N=768, T=8, H=128, F=128, NZ=64, G=64, D=320, n_next=12
// ws float offsets (total ~2.64 MB). Weights stored fp32 in k-chunked layout:
//   WT4[kc][row][4] : float4 per (kc,row), element j = W[row][4*kc+j]
#define H_OFF    0         // f32 [768][128]
#define C_OFF    98304     // f32 [768][128]
#define G_OFF    196608    // f32 [768][64]
#define S0_OFF   245760    // f32 [768]
#define WTD_OFF  246528    // f32 [768][128]
#define TIH_OFF  344832    // f32 [32][512][4]  (Wih, k=128)
#define THH_OFF  410368    // f32 [32][512][4]  (Whh)
#define TD1_OFF  475904    // f32 [80][320][4]  (Wd1, k=320)
#define TD2_OFF  578304    // f32 [80][160][4]  (Wd2, k=320)
#define TD3_OFF  629504    // f32 [40][80][4]   (Wd3, k=160)
#define TWA_OFF  642304    // f32 [128][128] (WaT)
#define BZ_OFF   658688    // f32 [512] (bih+bhh)

__device__ __forceinline__ float sigm(float x) { return 1.0f / (1.0f + __expf(-x)); }
__device__ __forceinline__ float lrelu(float u) { return u >= 0.f ? u : 0.2f * u; }

#define FMA4(acc_, w_, x_) acc_ += w_.x*x_.x + w_.y*x_.y + w_.z*x_.z + w_.w*x_.w

// ---------------- one-time weight re-layout + bias fold ----------------
__global__ __launch_bounds__(256) void k_tr(
    const float* __restrict__ Wih, const float* __restrict__ Whh,
    const float* __restrict__ Wd1, const float* __restrict__ Wd2,
    const float* __restrict__ Wd3, const float* __restrict__ Wa,
    const float* __restrict__ bih, const float* __restrict__ bhh,
    float* __restrict__ ws)
{
  const int idx = blockIdx.x * 256 + threadIdx.x;
  if (idx < 65536) {  // [512][128] -> [32][512][4]
    int j = idx & 3, r = (idx >> 2) & 511, kc = idx >> 11;
    ws[TIH_OFF + idx] = Wih[(size_t)r * 128 + kc * 4 + j];
    ws[THH_OFF + idx] = Whh[(size_t)r * 128 + kc * 4 + j];
  }
  if (idx < 102400) { // [320][320] -> [80][320][4]
    int j = idx & 3, t = idx >> 2; int r = t % 320, kc = t / 320;
    ws[TD1_OFF + idx] = Wd1[(size_t)r * 320 + kc * 4 + j];
  }
  if (idx < 51200) {  // [160][320] -> [80][160][4]
    int j = idx & 3, t = idx >> 2; int r = t % 160, kc = t / 160;
    ws[TD2_OFF + idx] = Wd2[(size_t)r * 320 + kc * 4 + j];
  }
  if (idx < 12800) {  // [80][160] -> [40][80][4]
    int j = idx & 3, t = idx >> 2; int r = t % 80, kc = t / 80;
    ws[TD3_OFF + idx] = Wd3[(size_t)r * 160 + kc * 4 + j];
  }
  if (idx < 16384) { int k = idx >> 7, r = idx & 127; ws[TWA_OFF + idx] = Wa[(size_t)r * 128 + k]; }
  if (idx < 512)   ws[BZ_OFF + idx] = bih[idx] + bhh[idx];
}

// ---------------- encoder LSTM: emb fused, 3 agents/block, 8 waves ----------------
__global__ __launch_bounds__(512) void k_enc(
    const float* __restrict__ obsv, const float* __restrict__ Wemb,
    const float* __restrict__ bemb, float* __restrict__ ws)
{
  __shared__ float hS[3][128], cS[3][128], zS[3][512], xeS[3][128];
  __shared__ float WembS[512], bembS[128];
  const int tid = threadIdx.x;
  const int wid = tid >> 6, lane = tid & 63;
  const int n0 = blockIdx.x * 3;
  const int row = wid * 64 + lane;

  WembS[tid] = Wemb[tid];
  if (tid < 128) bembS[tid] = bemb[tid];
  if (tid < 384) { int a = tid >> 7, j = tid & 127; hS[a][j] = 0.f; cS[a][j] = 0.f; }
  __syncthreads();

  const float bzv = ws[BZ_OFF + row];
  const float4* wih4 = (const float4*)(ws + TIH_OFF) + row;
  const float4* whh4 = (const float4*)(ws + THH_OFF) + row;

  for (int step = 0; step < 8; ++step) {
    if (tid < 384) {
      int a = tid >> 7, j = tid & 127;
      float4 ob = *(const float4*)&obsv[((size_t)(n0 + a) * 8 + step) * 4];
      float4 w = *(const float4*)&WembS[j * 4];
      xeS[a][j] = bembS[j] + ob.x * w.x + ob.y * w.y + ob.z * w.z + ob.w * w.w;
    }
    __syncthreads();
    float a0 = bzv, a1 = bzv, a2 = bzv;
#pragma unroll 4
    for (int kc = 0; kc < 32; ++kc) {
      float4 w = wih4[kc * 512];
      float4 x0 = *(const float4*)&xeS[0][kc * 4];
      float4 x1 = *(const float4*)&xeS[1][kc * 4];
      float4 x2 = *(const float4*)&xeS[2][kc * 4];
      FMA4(a0, w, x0); FMA4(a1, w, x1); FMA4(a2, w, x2);
    }
    if (step > 0) {
#pragma unroll 4
      for (int kc = 0; kc < 32; ++kc) {
        float4 w = whh4[kc * 512];
        float4 h0 = *(const float4*)&hS[0][kc * 4];
        float4 h1 = *(const float4*)&hS[1][kc * 4];
        float4 h2 = *(const float4*)&hS[2][kc * 4];
        FMA4(a0, w, h0); FMA4(a1, w, h1); FMA4(a2, w, h2);
      }
    }
    zS[0][row] = a0; zS[1][row] = a1; zS[2][row] = a2;
    __syncthreads();
    if (tid < 384) {
      int a = tid >> 7, j = tid & 127;
      float ci = sigm(zS[a][j + 128]) * cS[a][j] + sigm(zS[a][j]) * tanhf(zS[a][j + 256]);
      cS[a][j] = ci;
      hS[a][j] = sigm(zS[a][j + 384]) * tanhf(ci);
    }
    __syncthreads();
  }
  if (tid < 384) {
    int a = tid >> 7, j = tid & 127;
    ws[H_OFF + (size_t)(n0 + a) * 128 + j] = hS[a][j];
    ws[C_OFF + (size_t)(n0 + a) * 128 + j] = cS[a][j];
  }
}

// ---------------- social fold: Wh = h@Wa^T + ba ; g = Wf3^T Wh ; s0 = bf3 . Wh ----------------
__global__ __launch_bounds__(128) void k_social(
    const float* __restrict__ ba, const float* __restrict__ Wf3,
    const float* __restrict__ bf3, float* __restrict__ ws)
{
  __shared__ float hsh[128];
  __shared__ float Wh[128];
  const int n = blockIdx.x, t = threadIdx.x;
  hsh[t] = ws[H_OFF + (size_t)n * 128 + t];
  __syncthreads();
  float acc = ba[t];
#pragma unroll 8
  for (int k = 0; k < 128; ++k) acc += ws[TWA_OFF + (size_t)k * 128 + t] * hsh[k];
  Wh[t] = acc;
  __syncthreads();
  if (t < 64) {
    float g = 0.f;
#pragma unroll 8
    for (int f = 0; f < 128; ++f) g += Wf3[(size_t)f * 64 + t] * Wh[f];
    ws[G_OFF + (size_t)n * 64 + t] = g;
  } else {
    int l = t - 64;
    float p = bf3[l] * Wh[l] + bf3[l + 64] * Wh[l + 64];
    for (int off = 32; off > 0; off >>= 1) p += __shfl_xor(p, off);
    if (l == 0) ws[S0_OFF + n] = p;
  }
}

// ---------------- pair features + MLP(3->32->64) + sigma + softmax + S ----------------
__global__ __launch_bounds__(64) void k_attn(
    const float* __restrict__ obsv, const float* __restrict__ Wf1,
    const float* __restrict__ bf1, const float* __restrict__ Wf2,
    const float* __restrict__ bf2, float* __restrict__ ws)
{
  __shared__ float w1[96];
  __shared__ float b1[32];
  __shared__ float w2[2048];
  __shared__ float b2[64];
  __shared__ float attn_s[64];
  __shared__ float xi[4];

  const int i = blockIdx.x;
  const int b = i >> 6;
  const int lane = threadIdx.x;
  const int jn = (b << 6) + lane;

  for (int e = lane; e < 96; e += 64) w1[e] = Wf1[e];
  if (lane < 32) b1[lane] = bf1[lane];
  for (int e = lane; e < 2048; e += 64) w2[e] = Wf2[e];
  b2[lane] = bf2[lane];
  if (lane < 4) xi[lane] = obsv[((size_t)i * 8 + 7) * 4 + lane];
  __syncthreads();

  float4 xj = *(const float4*)&obsv[((size_t)jn * 8 + 7) * 4];
  float dpx = xi[0] - xj.x, dpy = xi[1] - xj.y;
  float vix = xi[2], viy = xi[3];
  float dvx = vix - xj.z, dvy = viy - xj.w;
  float l2 = sqrtf(dpx * dpx + dpy * dpy);
  float vnorm = sqrtf(vix * vix + viy * viy);
  float cosv = (dpx * vix + dpy * viy) / (l2 * vnorm + 1e-6f);
  float dv2 = dvx * dvx + dvy * dvy;
  float ttca = -(dpx * dvx + dpy * dvy) / (dv2 + 1e-6f);
  float cax = dpx + ttca * dvx, cay = dpy + ttca * dvy;
  float dca = sqrtf(cax * cax + cay * cay);

  float e1[32];
#pragma unroll
  for (int r = 0; r < 32; ++r)
    e1[r] = fmaxf(w1[r * 3 + 0] * l2 + w1[r * 3 + 1] * cosv + w1[r * 3 + 2] * dca + b1[r], 0.f);

  const float* gp = &ws[G_OFF + (size_t)jn * 64];
  float sig = ws[S0_OFF + jn];
  for (int r = 0; r < 64; ++r) {
    float a2 = b2[r];
#pragma unroll
    for (int k4 = 0; k4 < 8; ++k4) {
      float4 w = *(const float4*)&w2[r * 32 + k4 * 4];
      a2 += w.x * e1[k4 * 4 + 0] + w.y * e1[k4 * 4 + 1] + w.z * e1[k4 * 4 + 2] + w.w * e1[k4 * 4 + 3];
    }
    a2 = fmaxf(a2, 0.f);
    sig += a2 * gp[r];
  }
  if (lane == (i & 63)) sig = -1000.f;

  float m = sig;
  for (int off = 32; off > 0; off >>= 1) m = fmaxf(m, __shfl_xor(m, off));
  float ex = __expf(sig - m);
  float ssum = ex;
  for (int off = 32; off > 0; off >>= 1) ssum += __shfl_xor(ssum, off);
  attn_s[lane] = ex / ssum;
  __syncthreads();

  const float* hbase = &ws[H_OFF + (size_t)(b << 6) * 128];
  float s0a = 0.f, s1a = 0.f;
  for (int j = 0; j < 64; ++j) {
    float aj = attn_s[j];
    s0a += aj * hbase[(size_t)j * 128 + lane];
    s1a += aj * hbase[(size_t)j * 128 + 64 + lane];
  }
  ws[WTD_OFF + (size_t)i * 128 + lane] = s0a;
  ws[WTD_OFF + (size_t)i * 128 + 64 + lane] = s1a;
}

// ---------------- decoder: 12 fused steps, 3 agents/block, grid 256 ----------------
__global__ __launch_bounds__(512) void k_dec(
    const float* __restrict__ obsv, const float* __restrict__ noise,
    const float* __restrict__ Wemb, const float* __restrict__ bemb,
    const float* __restrict__ bd1, const float* __restrict__ bd2,
    const float* __restrict__ bd3, const float* __restrict__ bd4,
    const float* __restrict__ Wd4,
    float* __restrict__ ws, float* __restrict__ out)
{
  __shared__ float inpS[3][320], u1S[3][320], u2S[3][160], u3S[3][80];
  __shared__ float cS[3][128], xeS[3][128], zS[3][512];
  __shared__ float lastS[3][4];
  __shared__ float bd1S[320], bd2S[160], bd3S[80], bd4S[2], Wd4S[160];
  __shared__ float WembS[512], bembS[128], bzS[512];

  const int tid = threadIdx.x;
  const int wid = tid >> 6, lane = tid & 63;
  const int n0 = blockIdx.x * 3;

  if (tid < 384) {
    int a = tid >> 7, j = tid & 127;
    inpS[a][j] = ws[H_OFF + (size_t)(n0 + a) * 128 + j];
    inpS[a][128 + j] = ws[WTD_OFF + (size_t)(n0 + a) * 128 + j];
    if (j < 64) inpS[a][256 + j] = noise[(size_t)(n0 + a) * 64 + j];
    cS[a][j] = ws[C_OFF + (size_t)(n0 + a) * 128 + j];
  }
  WembS[tid] = Wemb[tid];
  bzS[tid] = ws[BZ_OFF + tid];
  if (tid < 320) bd1S[tid] = bd1[tid];
  if (tid < 160) { bd2S[tid] = bd2[tid]; Wd4S[tid] = Wd4[tid]; }
  if (tid < 128) bembS[tid] = bemb[tid];
  if (tid < 80) bd3S[tid] = bd3[tid];
  if (tid < 2) bd4S[tid] = bd4[tid];
  if (tid < 12) {
    int a = tid >> 2, r = tid & 3;
    lastS[a][r] = obsv[((size_t)(n0 + a) * 8 + 7) * 4 + r];
  }
  __syncthreads();

  const float4* wd1c = (const float4*)(ws + TD1_OFF);
  const float4* wd2c = (const float4*)(ws + TD2_OFF);
  const float4* wd3c = (const float4*)(ws + TD3_OFF);
  const float4* wih4 = (const float4*)(ws + TIH_OFF);
  const float4* whh4 = (const float4*)(ws + THH_OFF);

  for (int s = 0; s < 12; ++s) {
    // u1 = lrelu(inp @ Wd1^T + bd1): 320 rows, waves 0..4 row-stationary
    if (wid < 5) {
      const int r = wid * 64 + lane;
      float a0 = bd1S[r], a1 = a0, a2 = a0;
      const float4* wp = wd1c + r;
#pragma unroll 4
      for (int kc = 0; kc < 80; ++kc) {
        float4 w = wp[kc * 320];
        float4 x0 = *(const float4*)&inpS[0][kc * 4];
        float4 x1 = *(const float4*)&inpS[1][kc * 4];
        float4 x2 = *(const float4*)&inpS[2][kc * 4];
        FMA4(a0, w, x0); FMA4(a1, w, x1); FMA4(a2, w, x2);
      }
      u1S[0][r] = lrelu(a0); u1S[1][r] = lrelu(a1); u1S[2][r] = lrelu(a2);
    }
    __syncthreads();
    // u2: 160 rows, k=320 (80 chunks) split in 2 halves across lane groups
    if (wid < 5) {
      const int r = wid * 32 + (lane & 31);
      const int kb = (lane >> 5) * 40;
      float a0 = 0.f, a1 = 0.f, a2 = 0.f;
      const float4* wp = wd2c + r;
#pragma unroll 4
      for (int i2 = 0; i2 < 40; ++i2) {
        int kc = kb + i2;
        float4 w = wp[kc * 160];
        float4 x0 = *(const float4*)&u1S[0][kc * 4];
        float4 x1 = *(const float4*)&u1S[1][kc * 4];
        float4 x2 = *(const float4*)&u1S[2][kc * 4];
        FMA4(a0, w, x0); FMA4(a1, w, x1); FMA4(a2, w, x2);
      }
      a0 += __shfl_xor(a0, 32); a1 += __shfl_xor(a1, 32); a2 += __shfl_xor(a2, 32);
      if (lane < 32) {
        float bb = bd2S[r];
        u2S[0][r] = lrelu(a0 + bb); u2S[1][r] = lrelu(a1 + bb); u2S[2][r] = lrelu(a2 + bb);
      }
    }
    __syncthreads();
    // u3: 80 rows, k=160 (40 chunks) split in 4 quarters across lane groups
    if (wid < 5) {
      const int r = wid * 16 + (lane & 15);
      const int kb = (lane >> 4) * 10;
      float a0 = 0.f, a1 = 0.f, a2 = 0.f;
      const float4* wp = wd3c + r;
#pragma unroll 2
      for (int i2 = 0; i2 < 10; ++i2) {
        int kc = kb + i2;
        float4 w = wp[kc * 80];
        float4 x0 = *(const float4*)&u2S[0][kc * 4];
        float4 x1 = *(const float4*)&u2S[1][kc * 4];
        float4 x2 = *(const float4*)&u2S[2][kc * 4];
        FMA4(a0, w, x0); FMA4(a1, w, x1); FMA4(a2, w, x2);
      }
      a0 += __shfl_xor(a0, 16); a1 += __shfl_xor(a1, 16); a2 += __shfl_xor(a2, 16);
      a0 += __shfl_xor(a0, 32); a1 += __shfl_xor(a1, 32); a2 += __shfl_xor(a2, 32);
      if (lane < 16) {
        float bb = bd3S[r];
        u3S[0][r] = a0 + bb; u3S[1][r] = a1 + bb; u3S[2][r] = a2 + bb;
      }
    }
    __syncthreads();
    // v = u3 @ Wd4^T + bd4 (2 rows); position update; output
    if (wid < 3) {
      const int a = wid;
      float q0 = Wd4S[lane] * u3S[a][lane];
      float q1 = Wd4S[80 + lane] * u3S[a][lane];
      if (lane < 16) {
        q0 += Wd4S[64 + lane] * u3S[a][64 + lane];
        q1 += Wd4S[144 + lane] * u3S[a][64 + lane];
      }
      for (int off = 32; off > 0; off >>= 1) { q0 += __shfl_xor(q0, off); q1 += __shfl_xor(q1, off); }
      if (lane == 0) {
        float v0 = q0 + bd4S[0], v1 = q1 + bd4S[1];
        float p0 = v0 + lastS[a][0], p1 = v1 + lastS[a][1];
        lastS[a][0] = p0; lastS[a][1] = p1; lastS[a][2] = v0; lastS[a][3] = v1;
        float* op = &out[(size_t)(n0 + a) * 48 + s * 4];
        op[0] = p0; op[1] = p1; op[2] = v0; op[3] = v1;
      }
    }
    __syncthreads();
    // xe = new_last @ Wemb^T + bemb
    if (tid < 384) {
      int a = tid >> 7, j = tid & 127;
      float4 w = *(const float4*)&WembS[j * 4];
      xeS[a][j] = bembS[j] + lastS[a][0] * w.x + lastS[a][1] * w.y + lastS[a][2] * w.z + lastS[a][3] * w.w;
    }
    __syncthreads();
    // z = xe @ Wih^T + h @ Whh^T + bz: 512 rows, all 8 waves
    {
      const int row = wid * 64 + lane;
      float a0 = bzS[row], a1 = a0, a2 = a0;
      const float4* wi = wih4 + row;
      const float4* wh = whh4 + row;
#pragma unroll 4
      for (int kc = 0; kc < 32; ++kc) {
        float4 w = wi[kc * 512];
        float4 x0 = *(const float4*)&xeS[0][kc * 4];
        float4 x1 = *(const float4*)&xeS[1][kc * 4];
        float4 x2 = *(const float4*)&xeS[2][kc * 4];
        FMA4(a0, w, x0); FMA4(a1, w, x1); FMA4(a2, w, x2);
      }
#pragma unroll 4
      for (int kc = 0; kc < 32; ++kc) {
        float4 w = wh[kc * 512];
        float4 h0 = *(const float4*)&inpS[0][kc * 4];
        float4 h1 = *(const float4*)&inpS[1][kc * 4];
        float4 h2 = *(const float4*)&inpS[2][kc * 4];
        FMA4(a0, w, h0); FMA4(a1, w, h1); FMA4(a2, w, h2);
      }
      zS[0][row] = a0; zS[1][row] = a1; zS[2][row] = a2;
    }
    __syncthreads();
    // gates: update c and h (h lives in inpS[:, 0:128])
    if (tid < 384) {
      int a = tid >> 7, j = tid & 127;
      float ci = sigm(zS[a][j + 128]) * cS[a][j] + sigm(zS[a][j]) * tanhf(zS[a][j + 256]);
      cS[a][j] = ci;
      inpS[a][j] = sigm(zS[a][j + 384]) * tanhf(ci);
    }
    __syncthreads();
  }
}

extern "C" void kernel_launch(void* const* d_in, const int* in_sizes, int n_in,
                              void* d_out, int out_size, void* d_ws, size_t ws_size,
                              hipStream_t stream)
{
  const float* obsv = (const float*)d_in[0];
  const float* noise = (const float*)d_in[1];
  const float* Wemb = (const float*)d_in[2];
  const float* bemb = (const float*)d_in[3];
  const float* Wih = (const float*)d_in[4];
  const float* Whh = (const float*)d_in[5];
  const float* bih = (const float*)d_in[6];
  const float* bhh = (const float*)d_in[7];
  const float* Wf1 = (const float*)d_in[8];
  const float* bf1 = (const float*)d_in[9];
  const float* Wf2 = (const float*)d_in[10];
  const float* bf2 = (const float*)d_in[11];
  const float* Wf3 = (const float*)d_in[12];
  const float* bf3 = (const float*)d_in[13];
  const float* Wa = (const float*)d_in[14];
  const float* ba = (const float*)d_in[15];
  const float* Wd1 = (const float*)d_in[16];
  const float* bd1 = (const float*)d_in[17];
  const float* Wd2 = (const float*)d_in[18];
  const float* bd2 = (const float*)d_in[19];
  const float* Wd3 = (const float*)d_in[20];
  const float* bd3 = (const float*)d_in[21];
  const float* Wd4 = (const float*)d_in[22];
  const float* bd4 = (const float*)d_in[23];
  float* ws = (float*)d_ws;
  float* out = (float*)d_out;

  k_tr<<<400, 256, 0, stream>>>(Wih, Whh, Wd1, Wd2, Wd3, Wa, bih, bhh, ws);
  k_enc<<<256, 512, 0, stream>>>(obsv, Wemb, bemb, ws);
  k_social<<<768, 128, 0, stream>>>(ba, Wf3, bf3, ws);
  k_attn<<<768, 64, 0, stream>>>(obsv, Wf1, bf1, Wf2, bf2, ws);
  k_dec<<<256, 512, 0, stream>>>(obsv, noise, Wemb, bemb, bd1, bd2, bd3, bd4, Wd4, ws, out);
}

// Round 8
// 203.771 us; speedup vs baseline: 1.8368x; 1.5214x over previous
//
#include <hip/hip_runtime.h>
#include <math.h>

// N=768, T=8, H=128, F=128, NZ=64, G=64, D=320, n_next=12
// ws offsets in 4-byte units. Total ~2.57 MB.
#define H_OFF    0         // f32 [768][128]
#define C_OFF    98304     // f32 [768][128]
#define G_OFF    196608    // f32 [768][64]
#define S0_OFF   245760    // f32 [768]
#define WTD_OFF  246528    // f32 [768][128]
#define TIH_OFF  344832    // f32 [32][512][4]  (Wih enc k-chunk)
#define THH_OFF  410368    // f32 [32][512][4]
#define TWA_OFF  475904    // f32 [128][128] (WaT)
#define BZ_OFF   492288    // f32 [512] (bih+bhh)
// bf16 MFMA B-fragment packs (dwords): tile=(nt*KT+kt), 256 dwords/tile
#define PKD1_OFF 492800    // Wd1: NT=20 KT=10 -> 51200
#define PKD2_OFF 544000    // Wd2: NT=10 KT=10 -> 25600
#define PKD3_OFF 569600    // Wd3: NT=5  KT=5  -> 6400
#define PKIH_OFF 576000    // Wih: NT=32 KT=4  -> 32768
#define PKHH_OFF 608768    // Whh: NT=32 KT=4  -> 32768

typedef short s8v __attribute__((ext_vector_type(8)));
typedef float f4v __attribute__((ext_vector_type(4)));

__device__ __forceinline__ float sigm(float x) { return 1.0f / (1.0f + __expf(-x)); }
__device__ __forceinline__ float lrelu(float u) { return u >= 0.f ? u : 0.2f * u; }

__device__ __forceinline__ unsigned bf16rn(float f) {
  unsigned u = __float_as_uint(f);
  return (u + 0x7fffu + ((u >> 16) & 1u)) >> 16;
}
__device__ __forceinline__ unsigned pack2(float a, float b) {
  return bf16rn(a) | (bf16rn(b) << 16);
}
// fragment k-order bijection (same for A and B): k(g,e) = kt*32 + (e>>2)*16 + g*4 + (e&3)
// frag ushort index for element (a, k):
__device__ __forceinline__ int fidx(int a, int k) {
  int kt = k >> 5, kk = k & 31, half = kk >> 4, rem = kk & 15;
  return (kt * 64 + (rem >> 2) * 16 + a) * 8 + half * 4 + (rem & 3);
}

// ---------------- one-time: enc fp32 layout + MFMA bf16 B-frag packs + misc ----------------
__device__ __forceinline__ void packB(const float* __restrict__ W, int K, int KT,
                                      unsigned* __restrict__ dst, int idx) {
  int t = idx >> 8, r = idx & 255, lane = r >> 2, d = r & 3;
  int nt = t / KT, kt = t % KT;
  int n = nt * 16 + (lane & 15), g = lane >> 4;
  int e0 = 2 * d, e1 = 2 * d + 1;
  int k0 = kt * 32 + ((e0 >> 2) << 4) + g * 4 + (e0 & 3);
  int k1 = kt * 32 + ((e1 >> 2) << 4) + g * 4 + (e1 & 3);
  dst[idx] = pack2(W[(size_t)n * K + k0], W[(size_t)n * K + k1]);
}

__global__ __launch_bounds__(256) void k_tr(
    const float* __restrict__ Wih, const float* __restrict__ Whh,
    const float* __restrict__ Wd1, const float* __restrict__ Wd2,
    const float* __restrict__ Wd3, const float* __restrict__ Wa,
    const float* __restrict__ bih, const float* __restrict__ bhh,
    float* __restrict__ ws)
{
  const int idx = blockIdx.x * 256 + threadIdx.x;
  unsigned* wsu = (unsigned*)ws;
  if (idx < 65536) {  // enc fp32 [512][128] -> [32][512][4]
    int j = idx & 3, r = (idx >> 2) & 511, kc = idx >> 11;
    ws[TIH_OFF + idx] = Wih[(size_t)r * 128 + kc * 4 + j];
    ws[THH_OFF + idx] = Whh[(size_t)r * 128 + kc * 4 + j];
  }
  if (idx < 16384) { int k = idx >> 7, r = idx & 127; ws[TWA_OFF + idx] = Wa[(size_t)r * 128 + k]; }
  if (idx < 512)   ws[BZ_OFF + idx] = bih[idx] + bhh[idx];
  if (idx < 51200) packB(Wd1, 320, 10, wsu + PKD1_OFF, idx);
  if (idx < 25600) packB(Wd2, 320, 10, wsu + PKD2_OFF, idx);
  if (idx < 6400)  packB(Wd3, 160, 5,  wsu + PKD3_OFF, idx);
  if (idx < 32768) {
    packB(Wih, 128, 4, wsu + PKIH_OFF, idx);
    packB(Whh, 128, 4, wsu + PKHH_OFF, idx);
  }
}

// ---------------- encoder LSTM (unchanged from R6): fp32, 3 agents/block ----------------
__global__ __launch_bounds__(512) void k_enc(
    const float* __restrict__ obsv, const float* __restrict__ Wemb,
    const float* __restrict__ bemb, float* __restrict__ ws)
{
  __shared__ float hS[3][128], cS[3][128], zS[3][512], xeS[3][128];
  __shared__ float WembS[512], bembS[128];
  const int tid = threadIdx.x;
  const int wid = tid >> 6, lane = tid & 63;
  const int n0 = blockIdx.x * 3;
  const int row = wid * 64 + lane;

  WembS[tid] = Wemb[tid];
  if (tid < 128) bembS[tid] = bemb[tid];
  if (tid < 384) { int a = tid >> 7, j = tid & 127; hS[a][j] = 0.f; cS[a][j] = 0.f; }
  __syncthreads();

  const float bzv = ws[BZ_OFF + row];
  const float4* wih4 = (const float4*)(ws + TIH_OFF) + row;
  const float4* whh4 = (const float4*)(ws + THH_OFF) + row;

#define FMA4(acc_, w_, x_) acc_ += w_.x*x_.x + w_.y*x_.y + w_.z*x_.z + w_.w*x_.w
  for (int step = 0; step < 8; ++step) {
    if (tid < 384) {
      int a = tid >> 7, j = tid & 127;
      float4 ob = *(const float4*)&obsv[((size_t)(n0 + a) * 8 + step) * 4];
      float4 w = *(const float4*)&WembS[j * 4];
      xeS[a][j] = bembS[j] + ob.x * w.x + ob.y * w.y + ob.z * w.z + ob.w * w.w;
    }
    __syncthreads();
    float a0 = bzv, a1 = bzv, a2 = bzv;
#pragma unroll 4
    for (int kc = 0; kc < 32; ++kc) {
      float4 w = wih4[kc * 512];
      float4 x0 = *(const float4*)&xeS[0][kc * 4];
      float4 x1 = *(const float4*)&xeS[1][kc * 4];
      float4 x2 = *(const float4*)&xeS[2][kc * 4];
      FMA4(a0, w, x0); FMA4(a1, w, x1); FMA4(a2, w, x2);
    }
    if (step > 0) {
#pragma unroll 4
      for (int kc = 0; kc < 32; ++kc) {
        float4 w = whh4[kc * 512];
        float4 h0 = *(const float4*)&hS[0][kc * 4];
        float4 h1 = *(const float4*)&hS[1][kc * 4];
        float4 h2 = *(const float4*)&hS[2][kc * 4];
        FMA4(a0, w, h0); FMA4(a1, w, h1); FMA4(a2, w, h2);
      }
    }
    zS[0][row] = a0; zS[1][row] = a1; zS[2][row] = a2;
    __syncthreads();
    if (tid < 384) {
      int a = tid >> 7, j = tid & 127;
      float ci = sigm(zS[a][j + 128]) * cS[a][j] + sigm(zS[a][j]) * tanhf(zS[a][j + 256]);
      cS[a][j] = ci;
      hS[a][j] = sigm(zS[a][j + 384]) * tanhf(ci);
    }
    __syncthreads();
  }
  if (tid < 384) {
    int a = tid >> 7, j = tid & 127;
    ws[H_OFF + (size_t)(n0 + a) * 128 + j] = hS[a][j];
    ws[C_OFF + (size_t)(n0 + a) * 128 + j] = cS[a][j];
  }
}

// ---------------- social fold (unchanged) ----------------
__global__ __launch_bounds__(128) void k_social(
    const float* __restrict__ ba, const float* __restrict__ Wf3,
    const float* __restrict__ bf3, float* __restrict__ ws)
{
  __shared__ float hsh[128];
  __shared__ float Wh[128];
  const int n = blockIdx.x, t = threadIdx.x;
  hsh[t] = ws[H_OFF + (size_t)n * 128 + t];
  __syncthreads();
  float acc = ba[t];
#pragma unroll 8
  for (int k = 0; k < 128; ++k) acc += ws[TWA_OFF + (size_t)k * 128 + t] * hsh[k];
  Wh[t] = acc;
  __syncthreads();
  if (t < 64) {
    float g = 0.f;
#pragma unroll 8
    for (int f = 0; f < 128; ++f) g += Wf3[(size_t)f * 64 + t] * Wh[f];
    ws[G_OFF + (size_t)n * 64 + t] = g;
  } else {
    int l = t - 64;
    float p = bf3[l] * Wh[l] + bf3[l + 64] * Wh[l + 64];
    for (int off = 32; off > 0; off >>= 1) p += __shfl_xor(p, off);
    if (l == 0) ws[S0_OFF + n] = p;
  }
}

// ---------------- attention (unchanged) ----------------
__global__ __launch_bounds__(64) void k_attn(
    const float* __restrict__ obsv, const float* __restrict__ Wf1,
    const float* __restrict__ bf1, const float* __restrict__ Wf2,
    const float* __restrict__ bf2, float* __restrict__ ws)
{
  __shared__ float w1[96];
  __shared__ float b1[32];
  __shared__ float w2[2048];
  __shared__ float b2[64];
  __shared__ float attn_s[64];
  __shared__ float xi[4];

  const int i = blockIdx.x;
  const int b = i >> 6;
  const int lane = threadIdx.x;
  const int jn = (b << 6) + lane;

  for (int e = lane; e < 96; e += 64) w1[e] = Wf1[e];
  if (lane < 32) b1[lane] = bf1[lane];
  for (int e = lane; e < 2048; e += 64) w2[e] = Wf2[e];
  b2[lane] = bf2[lane];
  if (lane < 4) xi[lane] = obsv[((size_t)i * 8 + 7) * 4 + lane];
  __syncthreads();

  float4 xj = *(const float4*)&obsv[((size_t)jn * 8 + 7) * 4];
  float dpx = xi[0] - xj.x, dpy = xi[1] - xj.y;
  float vix = xi[2], viy = xi[3];
  float dvx = vix - xj.z, dvy = viy - xj.w;
  float l2 = sqrtf(dpx * dpx + dpy * dpy);
  float vnorm = sqrtf(vix * vix + viy * viy);
  float cosv = (dpx * vix + dpy * viy) / (l2 * vnorm + 1e-6f);
  float dv2 = dvx * dvx + dvy * dvy;
  float ttca = -(dpx * dvx + dpy * dvy) / (dv2 + 1e-6f);
  float cax = dpx + ttca * dvx, cay = dpy + ttca * dvy;
  float dca = sqrtf(cax * cax + cay * cay);

  float e1[32];
#pragma unroll
  for (int r = 0; r < 32; ++r)
    e1[r] = fmaxf(w1[r * 3 + 0] * l2 + w1[r * 3 + 1] * cosv + w1[r * 3 + 2] * dca + b1[r], 0.f);

  const float* gp = &ws[G_OFF + (size_t)jn * 64];
  float sig = ws[S0_OFF + jn];
  for (int r = 0; r < 64; ++r) {
    float a2 = b2[r];
#pragma unroll
    for (int k4 = 0; k4 < 8; ++k4) {
      float4 w = *(const float4*)&w2[r * 32 + k4 * 4];
      a2 += w.x * e1[k4 * 4 + 0] + w.y * e1[k4 * 4 + 1] + w.z * e1[k4 * 4 + 2] + w.w * e1[k4 * 4 + 3];
    }
    a2 = fmaxf(a2, 0.f);
    sig += a2 * gp[r];
  }
  if (lane == (i & 63)) sig = -1000.f;

  float m = sig;
  for (int off = 32; off > 0; off >>= 1) m = fmaxf(m, __shfl_xor(m, off));
  float ex = __expf(sig - m);
  float ssum = ex;
  for (int off = 32; off > 0; off >>= 1) ssum += __shfl_xor(ssum, off);
  attn_s[lane] = ex / ssum;
  __syncthreads();

  const float* hbase = &ws[H_OFF + (size_t)(b << 6) * 128];
  float s0a = 0.f, s1a = 0.f;
  for (int j = 0; j < 64; ++j) {
    float aj = attn_s[j];
    s0a += aj * hbase[(size_t)j * 128 + lane];
    s1a += aj * hbase[(size_t)j * 128 + 64 + lane];
  }
  ws[WTD_OFF + (size_t)i * 128 + lane] = s0a;
  ws[WTD_OFF + (size_t)i * 128 + 64 + lane] = s1a;
}

// ---------------- decoder: MFMA, 16 agents/block, grid 48 ----------------
__global__ __launch_bounds__(512) void k_dec(
    const float* __restrict__ obsv, const float* __restrict__ noise,
    const float* __restrict__ Wemb, const float* __restrict__ bemb,
    const float* __restrict__ bd1, const float* __restrict__ bd2,
    const float* __restrict__ bd3, const float* __restrict__ bd4,
    const float* __restrict__ Wd4,
    float* __restrict__ ws, float* __restrict__ out)
{
  __shared__ __align__(16) unsigned short inpF[10 * 64 * 8];  // A-frags: [h(k0..127)|wtd|noise]
  __shared__ __align__(16) unsigned short u1F[10 * 64 * 8];
  __shared__ __align__(16) unsigned short u2F[5 * 64 * 8];
  __shared__ __align__(16) unsigned short xeF[4 * 64 * 8];
  __shared__ float zS[16 * 512];
  __shared__ float u3S[16 * 80];
  __shared__ float cS[16 * 128];
  __shared__ float lastS[16 * 4];
  __shared__ float bd1S[320], bd2S[160], bd3S[80], bd4S[2], Wd4S[160];
  __shared__ float bzS[512], WembS[512], bembS[128];

  const int tid = threadIdx.x;
  const int wid = tid >> 6, lane = tid & 63;
  const int n0 = blockIdx.x * 16;
  const int la = lane & 15, lg = lane >> 4;   // frag col / group
  const int abase = lg * 4;                    // C-row base (agent)

  const unsigned* pkd1 = (const unsigned*)(ws) + PKD1_OFF;
  const unsigned* pkd2 = (const unsigned*)(ws) + PKD2_OFF;
  const unsigned* pkd3 = (const unsigned*)(ws) + PKD3_OFF;
  const unsigned* pkih = (const unsigned*)(ws) + PKIH_OFF;
  const unsigned* pkhh = (const unsigned*)(ws) + PKHH_OFF;

  // ---- init ----
  {
    int a = tid & 15, jj = tid >> 4;  // jj in 0..31
#pragma unroll 4
    for (int p = 0; p < 4; ++p) {
      int j = jj + 32 * p;
      float hv = ws[H_OFF + (size_t)(n0 + a) * 128 + j];
      cS[a * 128 + j] = ws[C_OFF + (size_t)(n0 + a) * 128 + j];
      inpF[fidx(a, j)] = (unsigned short)bf16rn(hv);
      float wv = ws[WTD_OFF + (size_t)(n0 + a) * 128 + j];
      inpF[fidx(a, 128 + j)] = (unsigned short)bf16rn(wv);
    }
#pragma unroll 2
    for (int p = 0; p < 2; ++p) {
      int j = jj + 32 * p;
      float nv = noise[(size_t)(n0 + a) * 64 + j];
      inpF[fidx(a, 256 + j)] = (unsigned short)bf16rn(nv);
    }
  }
  if (tid < 64) lastS[tid] = obsv[((size_t)(n0 + (tid >> 2)) * 8 + 7) * 4 + (tid & 3)];
  WembS[tid] = Wemb[tid];
  bzS[tid] = ws[BZ_OFF + tid];
  if (tid < 320) bd1S[tid] = bd1[tid];
  if (tid < 160) { bd2S[tid] = bd2[tid]; Wd4S[tid] = Wd4[tid]; }
  if (tid < 128) bembS[tid] = bemb[tid];
  if (tid < 80) bd3S[tid] = bd3[tid];
  if (tid < 2) bd4S[tid] = bd4[tid];
  __syncthreads();

  for (int s = 0; s < 12; ++s) {
    // ---- U1: [16x320] = inp(320) x Wd1^T, MFMA, lrelu -> u1F ----
    for (int nt = wid; nt < 20; nt += 8) {
      f4v acc = {0.f, 0.f, 0.f, 0.f};
#pragma unroll
      for (int kt = 0; kt < 10; ++kt) {
        s8v A = *(const s8v*)&inpF[(kt * 64 + lane) * 8];
        s8v B = *(const s8v*)(pkd1 + ((size_t)(nt * 10 + kt) * 64 + lane) * 4);
        acc = __builtin_amdgcn_mfma_f32_16x16x32_bf16(A, B, acc, 0, 0, 0);
      }
      int n = nt * 16 + la;
      float bias = bd1S[n];
#pragma unroll 4
      for (int r = 0; r < 4; ++r)
        u1F[fidx(abase + r, n)] = (unsigned short)bf16rn(lrelu(acc[r] + bias));
    }
    __syncthreads();
    // ---- U2: [16x160] = u1(320) x Wd2^T ----
    for (int nt = wid; nt < 10; nt += 8) {
      f4v acc = {0.f, 0.f, 0.f, 0.f};
#pragma unroll
      for (int kt = 0; kt < 10; ++kt) {
        s8v A = *(const s8v*)&u1F[(kt * 64 + lane) * 8];
        s8v B = *(const s8v*)(pkd2 + ((size_t)(nt * 10 + kt) * 64 + lane) * 4);
        acc = __builtin_amdgcn_mfma_f32_16x16x32_bf16(A, B, acc, 0, 0, 0);
      }
      int n = nt * 16 + la;
      float bias = bd2S[n];
#pragma unroll 4
      for (int r = 0; r < 4; ++r)
        u2F[fidx(abase + r, n)] = (unsigned short)bf16rn(lrelu(acc[r] + bias));
    }
    __syncthreads();
    // ---- U3: [16x80] = u2(160) x Wd3^T (no act) -> u3S fp32 ----
    for (int nt = wid; nt < 5; nt += 8) {
      f4v acc = {0.f, 0.f, 0.f, 0.f};
#pragma unroll
      for (int kt = 0; kt < 5; ++kt) {
        s8v A = *(const s8v*)&u2F[(kt * 64 + lane) * 8];
        s8v B = *(const s8v*)(pkd3 + ((size_t)(nt * 5 + kt) * 64 + lane) * 4);
        acc = __builtin_amdgcn_mfma_f32_16x16x32_bf16(A, B, acc, 0, 0, 0);
      }
      int n = nt * 16 + la;
      float bias = bd3S[n];
#pragma unroll 4
      for (int r = 0; r < 4; ++r)
        u3S[(abase + r) * 80 + n] = acc[r] + bias;
    }
    __syncthreads();
    // ---- V: v = u3 @ Wd4^T + bd4 (2 per agent); last update; out write ----
    if (tid < 128) {
      int a = tid >> 3, r = (tid >> 2) & 1, q = tid & 3;
      float part = 0.f;
#pragma unroll 4
      for (int i = q * 20; i < q * 20 + 20; ++i)
        part += Wd4S[r * 80 + i] * u3S[a * 80 + i];
      part += __shfl_xor(part, 1);
      part += __shfl_xor(part, 2);
      if (q == 0) {
        float v = part + bd4S[r];
        float p = v + lastS[a * 4 + r];
        lastS[a * 4 + r] = p;
        lastS[a * 4 + 2 + r] = v;
        out[(size_t)(n0 + a) * 48 + s * 4 + r] = p;
        out[(size_t)(n0 + a) * 48 + s * 4 + 2 + r] = v;
      }
    }
    __syncthreads();
    // ---- XE: xe = new_last @ Wemb^T + bemb -> xeF ----
    {
      int a = tid & 15, jj = tid >> 4;
      float l0 = lastS[a * 4 + 0], l1 = lastS[a * 4 + 1];
      float l2v = lastS[a * 4 + 2], l3 = lastS[a * 4 + 3];
#pragma unroll 4
      for (int p = 0; p < 4; ++p) {
        int j = jj + 32 * p;
        float xv = bembS[j] + l0 * WembS[j * 4 + 0] + l1 * WembS[j * 4 + 1]
                 + l2v * WembS[j * 4 + 2] + l3 * WembS[j * 4 + 3];
        xeF[fidx(a, j)] = (unsigned short)bf16rn(xv);
      }
    }
    __syncthreads();
    // ---- Z: [16x512] = xe x Wih^T + h x Whh^T + bz -> zS fp32 ----
    for (int nt = wid; nt < 32; nt += 8) {
      f4v acc = {0.f, 0.f, 0.f, 0.f};
#pragma unroll
      for (int kt = 0; kt < 4; ++kt) {
        s8v A = *(const s8v*)&xeF[(kt * 64 + lane) * 8];
        s8v B = *(const s8v*)(pkih + ((size_t)(nt * 4 + kt) * 64 + lane) * 4);
        acc = __builtin_amdgcn_mfma_f32_16x16x32_bf16(A, B, acc, 0, 0, 0);
      }
#pragma unroll
      for (int kt = 0; kt < 4; ++kt) {
        s8v A = *(const s8v*)&inpF[(kt * 64 + lane) * 8];  // h region k=0..127
        s8v B = *(const s8v*)(pkhh + ((size_t)(nt * 4 + kt) * 64 + lane) * 4);
        acc = __builtin_amdgcn_mfma_f32_16x16x32_bf16(A, B, acc, 0, 0, 0);
      }
      int n = nt * 16 + la;
      float bz = bzS[n];
#pragma unroll 4
      for (int r = 0; r < 4; ++r)
        zS[(abase + r) * 512 + n] = acc[r] + bz;
    }
    __syncthreads();
    // ---- GATES: c,h update; h -> inpF (bf16 frag) ----
    {
      int a = tid & 15, jj = tid >> 4;
#pragma unroll 4
      for (int p = 0; p < 4; ++p) {
        int j = jj + 32 * p;
        float zi = zS[a * 512 + j];
        float zf = zS[a * 512 + 128 + j];
        float zg = zS[a * 512 + 256 + j];
        float zo = zS[a * 512 + 384 + j];
        float ci = sigm(zf) * cS[a * 128 + j] + sigm(zi) * tanhf(zg);
        cS[a * 128 + j] = ci;
        float hv = sigm(zo) * tanhf(ci);
        inpF[fidx(a, j)] = (unsigned short)bf16rn(hv);
      }
    }
    __syncthreads();
  }
}

extern "C" void kernel_launch(void* const* d_in, const int* in_sizes, int n_in,
                              void* d_out, int out_size, void* d_ws, size_t ws_size,
                              hipStream_t stream)
{
  const float* obsv = (const float*)d_in[0];
  const float* noise = (const float*)d_in[1];
  const float* Wemb = (const float*)d_in[2];
  const float* bemb = (const float*)d_in[3];
  const float* Wih = (const float*)d_in[4];
  const float* Whh = (const float*)d_in[5];
  const float* bih = (const float*)d_in[6];
  const float* bhh = (const float*)d_in[7];
  const float* Wf1 = (const float*)d_in[8];
  const float* bf1 = (const float*)d_in[9];
  const float* Wf2 = (const float*)d_in[10];
  const float* bf2 = (const float*)d_in[11];
  const float* Wf3 = (const float*)d_in[12];
  const float* bf3 = (const float*)d_in[13];
  const float* Wa = (const float*)d_in[14];
  const float* ba = (const float*)d_in[15];
  const float* Wd1 = (const float*)d_in[16];
  const float* bd1 = (const float*)d_in[17];
  const float* Wd2 = (const float*)d_in[18];
  const float* bd2 = (const float*)d_in[19];
  const float* Wd3 = (const float*)d_in[20];
  const float* bd3 = (const float*)d_in[21];
  const float* Wd4 = (const float*)d_in[22];
  const float* bd4 = (const float*)d_in[23];
  float* ws = (float*)d_ws;
  float* out = (float*)d_out;

  k_tr<<<256, 256, 0, stream>>>(Wih, Whh, Wd1, Wd2, Wd3, Wa, bih, bhh, ws);
  k_enc<<<256, 512, 0, stream>>>(obsv, Wemb, bemb, ws);
  k_social<<<768, 128, 0, stream>>>(ba, Wf3, bf3, ws);
  k_attn<<<768, 64, 0, stream>>>(obsv, Wf1, bf1, Wf2, bf2, ws);
  k_dec<<<48, 512, 0, stream>>>(obsv, noise, Wemb, bemb, bd1, bd2, bd3, bd4, Wd4, ws, out);
}